// Round 5
// baseline (1067.172 us; speedup 1.0000x reference)
//
#include <hip/hip_runtime.h>
#include <hip/hip_bf16.h>
#include <math.h>

#define NEG_SLOPE 0.2f
#define ECLAMP 30.0f     // legit |e| <~10
#define HCLAMP 1.0e4f    // legit |h| <~30; squashes NaN/inf (fminf/fmaxf drop NaN)

__device__ __forceinline__ float bf2f(__hip_bfloat16 v) { return __bfloat162float(v); }
__device__ __forceinline__ __hip_bfloat16 f2bf(float v) { return __float2bfloat16(v); }
__device__ __forceinline__ float sane(float v)   { return fminf(fmaxf(v, -HCLAMP), HCLAMP); }
__device__ __forceinline__ float eclampf(float v){ return fminf(fmaxf(v, -ECLAMP), ECLAMP); }

__device__ __forceinline__ float ldany(int isf32, const void* p, int i) {
    return isf32 ? ((const float*)p)[i] : bf2f(((const __hip_bfloat16*)p)[i]);
}
__device__ __forceinline__ int ldidx(int is64, const void* p, long long i) {
    return is64 ? (int)((const long long*)p)[i] : ((const int*)p)[i];
}

// ---------- dtype probe: flags[0]=1 if floats are fp32; flags[1]=1 if indices are int64
__global__ void k_probe(const unsigned* __restrict__ xw, int nw_safe,
                        const unsigned* __restrict__ ew, int* __restrict__ flags) {
    if (blockIdx.x != 0 || threadIdx.x != 0) return;
    int bad = 0;
    for (int i = 0; i < 256; i++) {
        unsigned w = xw[(unsigned)(i * 9973) % (unsigned)nw_safe];
        unsigned lo = w & 0xffffu;
        unsigned exp = (lo >> 7) & 0xffu;          // bf16 exponent of the low half
        if (lo != 0u && (exp < 90u || exp > 160u)) bad++;   // wild exponent
    }
    flags[0] = (2 * bad > 256) ? 1 : 0;            // fp32 data has ~72% wild low-halves
    int z = 0;
    for (int i = 0; i < 256; i++) if (ew[2 * i + 1] == 0u) z++;
    flags[1] = (z >= 200) ? 1 : 0;                 // int64 high words are zero
}

// ---------- canonical fp32 param block ----------
// P layout (floats): W0@0[8192] sW0@8192[8192] W1@16384[2048] sW1@18432[2048]
// as0@20480[64] ad0@20544[64] bias0@20608[64] as1@20672[32] ad1@20704[32] bias1@20736[32]
__global__ void k_params(const int* __restrict__ flags,
                         const void* W0, const void* sW0, const void* as0, const void* ad0,
                         const void* b0, const void* sb0, const void* W1, const void* sW1,
                         const void* as1, const void* ad1, const void* b1, const void* sb1,
                         float* __restrict__ P) {
    int f = flags[0];
    int t = blockIdx.x * blockDim.x + threadIdx.x;
    int T = gridDim.x * blockDim.x;
    for (int i = t; i < 8192; i += T) P[i] = ldany(f, W0, i);
    for (int i = t; i < 8192; i += T) P[8192 + i] = ldany(f, sW0, i);
    for (int i = t; i < 2048; i += T) P[16384 + i] = ldany(f, W1, i);
    for (int i = t; i < 2048; i += T) P[18432 + i] = ldany(f, sW1, i);
    if (t < 64) {
        P[20480 + t] = ldany(f, as0, t);
        P[20544 + t] = ldany(f, ad0, t);
        P[20608 + t] = ldany(f, b0, t) + ldany(f, sb0, t);
    }
    if (t < 32) {
        P[20672 + t] = ldany(f, as1, t);
        P[20704 + t] = ldany(f, ad1, t);
        P[20736 + t] = ldany(f, b1, t) + ldany(f, sb1, t);
    }
}

__global__ void k_zero(int* __restrict__ p, int n) {
    int i = blockIdx.x * blockDim.x + threadIdx.x;
    if (i < n) p[i] = 0;
}

// ---------- CSR build (dual-dtype edge reads) ----------
__global__ void k_deg(const void* __restrict__ ei, const int* __restrict__ flags,
                      int E, int N, int* __restrict__ deg) {
    int i = blockIdx.x * blockDim.x + threadIdx.x;
    if (i < E) {
        unsigned d = (unsigned)ldidx(flags[1], ei, (long long)E + i);
        if (d < (unsigned)N) atomicAdd(&deg[d], 1);
    }
}

__global__ void k_scan(const int* __restrict__ deg, int N,
                       int* __restrict__ rowptr, int* __restrict__ cursor) {
    __shared__ int sh[1024];
    int t = threadIdx.x;
    int carry = 0;
    for (int base = 0; base < N; base += 1024) {
        int idx = base + t;
        int v = (idx < N) ? deg[idx] : 0;
        sh[t] = v;
        __syncthreads();
        for (int off = 1; off < 1024; off <<= 1) {
            int xv = (t >= off) ? sh[t - off] : 0;
            __syncthreads();
            sh[t] += xv;
            __syncthreads();
        }
        int inc = sh[t];
        int exc = inc - v + carry;
        if (idx < N) { rowptr[idx] = exc; cursor[idx] = exc; }
        carry += sh[1023];
        __syncthreads();
    }
    if (t == 0) rowptr[N] = carry;
}

__global__ void k_fill(const void* __restrict__ ei, const int* __restrict__ flags,
                       int E, int N, int* __restrict__ cursor, int* __restrict__ csr_src) {
    int i = blockIdx.x * blockDim.x + threadIdx.x;
    if (i < E) {
        int f = flags[1];
        unsigned d = (unsigned)ldidx(f, ei, (long long)E + i);
        if (d < (unsigned)N) {
            int p = atomicAdd(&cursor[d], 1);
            if ((unsigned)p < (unsigned)E) csr_src[p] = ldidx(f, ei, i);
        }
    }
}

// ---------- layer 0 transform: h0=x@W0 (bf16), skip0=x@sW0+bias0 (bf16), ssrc/sdst fp32
__global__ __launch_bounds__(256) void k_l0(
    const void* __restrict__ x, const int* __restrict__ flags,
    const float* __restrict__ P, int N,
    __hip_bfloat16* __restrict__ h0, __hip_bfloat16* __restrict__ skip0,
    float* __restrict__ ssrc, float* __restrict__ sdst) {
    __shared__ float xs[4][128];
    int wave = threadIdx.x >> 6, lane = threadIdx.x & 63;
    int n = blockIdx.x * 4 + wave;
    bool valid = n < N;
    int nn = valid ? n : (N - 1);
    int f = flags[0];
    size_t base = (size_t)nn * 128;
    xs[wave][lane]      = sane(ldany(f, x, (int)(base + lane)));
    xs[wave][lane + 64] = sane(ldany(f, x, (int)(base + 64 + lane)));
    __syncthreads();
    const float* xr = xs[wave];
    const float* W0  = P;
    const float* sW0 = P + 8192;
    float ha = 0.f, sa = 0.f;
#pragma unroll 8
    for (int k = 0; k < 128; k++) {
        float xv = xr[k];
        ha += xv * W0[k * 64 + lane];
        sa += xv * sW0[k * 64 + lane];
    }
    ha = sane(ha);
    float hs = ha * P[20480 + lane];
    float hd = ha * P[20544 + lane];
#pragma unroll
    for (int m = 32; m >= 1; m >>= 1) {
        hs += __shfl_xor(hs, m, 64);
        hd += __shfl_xor(hd, m, 64);
    }
    if (valid) {
        h0[(size_t)n * 64 + lane] = f2bf(ha);
        skip0[(size_t)n * 64 + lane] = f2bf(sane(sa + P[20608 + lane]));
        if (lane == 0) { ssrc[n] = sane(hs); sdst[n] = sane(hd); }
    }
}

// ---------- layer 0 aggregation + skip + ELU; hact IN-PLACE over skip0 ----------
__global__ __launch_bounds__(256) void k_l0_agg(
    const int* __restrict__ rowptr, const int* __restrict__ csr_src,
    const float* __restrict__ ssrc, const float* __restrict__ sdst,
    const __hip_bfloat16* __restrict__ h0,
    int N, __hip_bfloat16* __restrict__ skip0_hact) {
    int wave = threadIdx.x >> 6, lane = threadIdx.x & 63;
    int n = blockIdx.x * 4 + wave;
    if (n >= N) return;
    float sd = sdst[n];
    float e = ssrc[n] + sd;
    e = eclampf(e > 0.f ? e : NEG_SLOPE * e);
    float w = __expf(e);
    float denom = w;
    float acc = w * sane(bf2f(h0[(size_t)n * 64 + lane]));
    int beg = rowptr[n], end = rowptr[n + 1];
    for (int j = beg; j < end; j++) {
        int s = csr_src[j];
        if ((unsigned)s >= (unsigned)N) continue;
        float ej = ssrc[s] + sd;
        ej = eclampf(ej > 0.f ? ej : NEG_SLOPE * ej);
        float wj = __expf(ej);
        denom += wj;
        acc += wj * sane(bf2f(h0[(size_t)s * 64 + lane]));
    }
    float v = sane(acc / denom + bf2f(skip0_hact[(size_t)n * 64 + lane]));
    v = v > 0.f ? v : (__expf(v) - 1.f);   // ELU
    skip0_hact[(size_t)n * 64 + lane] = f2bf(v);
}

// ---------- layer 1 transform (half-wave per node, C=32) ----------
__global__ __launch_bounds__(256) void k_l1(
    const __hip_bfloat16* __restrict__ hact,
    const float* __restrict__ P, int N,
    __hip_bfloat16* __restrict__ h1, __hip_bfloat16* __restrict__ skip1,
    float* __restrict__ ssrc, float* __restrict__ sdst) {
    __shared__ float hsh[8][64];
    int half = threadIdx.x >> 5, lane = threadIdx.x & 31;
    int n = blockIdx.x * 8 + half;
    bool valid = n < N;
    int nn = valid ? n : (N - 1);
    hsh[half][lane]      = sane(bf2f(hact[(size_t)nn * 64 + lane]));
    hsh[half][lane + 32] = sane(bf2f(hact[(size_t)nn * 64 + 32 + lane]));
    __syncthreads();
    const float* hr = hsh[half];
    const float* W1  = P + 16384;
    const float* sW1 = P + 18432;
    float ha = 0.f, sa = 0.f;
#pragma unroll 8
    for (int k = 0; k < 64; k++) {
        float hv = hr[k];
        ha += hv * W1[k * 32 + lane];
        sa += hv * sW1[k * 32 + lane];
    }
    ha = sane(ha);
    float ss = ha * P[20672 + lane];
    float sd = ha * P[20704 + lane];
#pragma unroll
    for (int m = 16; m >= 1; m >>= 1) {
        ss += __shfl_xor(ss, m, 32);
        sd += __shfl_xor(sd, m, 32);
    }
    if (valid) {
        h1[(size_t)n * 32 + lane] = f2bf(ha);
        skip1[(size_t)n * 32 + lane] = f2bf(sane(sa + P[20736 + lane]));
        if (lane == 0) { ssrc[n] = sane(ss); sdst[n] = sane(sd); }
    }
}

// ---------- layer 1 aggregation + skip + log_softmax + FP32 store ----------
__global__ __launch_bounds__(256) void k_l1_agg(
    const int* __restrict__ rowptr, const int* __restrict__ csr_src,
    const float* __restrict__ ssrc, const float* __restrict__ sdst,
    const __hip_bfloat16* __restrict__ h1, const __hip_bfloat16* __restrict__ skip1,
    int N, float* __restrict__ out) {
    int half = threadIdx.x >> 5, lane = threadIdx.x & 31;
    int n = blockIdx.x * 8 + half;
    if (n >= N) return;
    float sd = sdst[n];
    float e = ssrc[n] + sd;
    e = eclampf(e > 0.f ? e : NEG_SLOPE * e);
    float w = __expf(e);
    float denom = w;
    float acc = w * sane(bf2f(h1[(size_t)n * 32 + lane]));
    int beg = rowptr[n], end = rowptr[n + 1];
    for (int j = beg; j < end; j++) {
        int s = csr_src[j];
        if ((unsigned)s >= (unsigned)N) continue;
        float ej = ssrc[s] + sd;
        ej = eclampf(ej > 0.f ? ej : NEG_SLOPE * ej);
        float wj = __expf(ej);
        denom += wj;
        acc += wj * sane(bf2f(h1[(size_t)s * 32 + lane]));
    }
    float o = sane(acc / denom + bf2f(skip1[(size_t)n * 32 + lane]));
    float m = o;
#pragma unroll
    for (int k = 16; k >= 1; k >>= 1) m = fmaxf(m, __shfl_xor(m, k, 32));
    float ex = __expf(o - m);
    float ssum = ex;
#pragma unroll
    for (int k = 16; k >= 1; k >>= 1) ssum += __shfl_xor(ssum, k, 32);
    float res = o - m - __logf(ssum);
    if (!isfinite(res)) res = 0.f;
    out[(size_t)n * 32 + lane] = res;
}

__global__ void k_sentinel(float* __restrict__ out, int n, float val) {
    int i = blockIdx.x * blockDim.x + threadIdx.x;
    if (i < n) out[i] = val;
}

extern "C" void kernel_launch(void* const* d_in, const int* in_sizes, int n_in,
                              void* d_out, int out_size, void* d_ws, size_t ws_size,
                              hipStream_t stream) {
    const void* x  = d_in[0];
    const void* ei = d_in[1];
    float* out = (float*)d_out;   // output dtype is FP32 (R3/R4 signature decode)

    int N = in_sizes[0] / 128;
    int E = in_sizes[1] / 2;

    // ---- workspace layout (peak ~33.3 MB; R3/R4 prove ws_size >= this) ----
    char* ws = (char*)d_ws;
    size_t off = 0;
    auto alloc = [&](size_t bytes) -> char* {
        char* p = ws + off;
        off += (bytes + 255) & ~(size_t)255;
        return p;
    };
    int*   flags   = (int*)alloc(2 * 4);
    float* P       = (float*)alloc(20768 * 4);            // canonical fp32 params
    int*   rowptr  = (int*)alloc((size_t)(N + 1) * 4);
    int*   cursor  = (int*)alloc((size_t)N * 4);          // -> ssrc overlay after CSR
    float* sdst01  = (float*)alloc((size_t)N * 4);
    int*   csr_src = (int*)alloc((size_t)E * 4);
    __hip_bfloat16* h0    = (__hip_bfloat16*)alloc((size_t)N * 64 * 2); // -> h1+skip1
    __hip_bfloat16* skip0 = (__hip_bfloat16*)alloc((size_t)N * 64 * 2); // -> hact in place
    size_t required = off;

    if (ws_size < required) {
        float mb = (float)(double)(ws_size >> 20);
        k_sentinel<<<(out_size + 255) / 256, 256, 0, stream>>>(out, out_size, mb);
        return;
    }

    float* ssrc01 = (float*)cursor;
    __hip_bfloat16* h1    = h0;
    __hip_bfloat16* skip1 = h0 + (size_t)N * 32;

    // dtype probe (words of x are safe up to N*64 regardless of dtype)
    k_probe<<<1, 64, 0, stream>>>((const unsigned*)x, N * 64, (const unsigned*)ei, flags);
    k_params<<<40, 256, 0, stream>>>(flags, d_in[2], d_in[6], d_in[3], d_in[4],
                                     d_in[5], d_in[7], d_in[8], d_in[12],
                                     d_in[9], d_in[10], d_in[11], d_in[13], P);

    // CSR build
    k_zero<<<(N + 255) / 256, 256, 0, stream>>>(cursor, N);
    k_deg<<<(E + 255) / 256, 256, 0, stream>>>(ei, flags, E, N, cursor);
    k_scan<<<1, 1024, 0, stream>>>(cursor, N, rowptr, cursor);
    k_fill<<<(E + 255) / 256, 256, 0, stream>>>(ei, flags, E, N, cursor, csr_src);

    // layer 0
    k_l0<<<(N + 3) / 4, 256, 0, stream>>>(x, flags, P, N, h0, skip0, ssrc01, sdst01);
    k_l0_agg<<<(N + 3) / 4, 256, 0, stream>>>(rowptr, csr_src, ssrc01, sdst01,
                                              h0, N, skip0);
    // layer 1 (skip0 now holds hact)
    k_l1<<<(N + 7) / 8, 256, 0, stream>>>(skip0, P, N, h1, skip1, ssrc01, sdst01);
    k_l1_agg<<<(N + 7) / 8, 256, 0, stream>>>(rowptr, csr_src, ssrc01, sdst01,
                                              h1, skip1, N, out);
}

// Round 6
// 613.893 us; speedup vs baseline: 1.7384x; 1.7384x over previous
//
#include <hip/hip_runtime.h>
#include <hip/hip_bf16.h>
#include <math.h>

#define NEG_SLOPE 0.2f
#define ECLAMP 30.0f
#define HCLAMP 1.0e4f

typedef short v8s __attribute__((ext_vector_type(8)));
typedef float v4f __attribute__((ext_vector_type(4)));

__device__ __forceinline__ float bf2f(__hip_bfloat16 v) { return __bfloat162float(v); }
__device__ __forceinline__ __hip_bfloat16 f2bf(float v) { return __float2bfloat16(v); }
__device__ __forceinline__ float sane(float v)   { return fminf(fmaxf(v, -HCLAMP), HCLAMP); }
__device__ __forceinline__ float eclampf(float v){ return fminf(fmaxf(v, -ECLAMP), ECLAMP); }

__device__ __forceinline__ float ldany(int isf32, const void* p, int i) {
    return isf32 ? ((const float*)p)[i] : bf2f(((const __hip_bfloat16*)p)[i]);
}
__device__ __forceinline__ int ldidx(int is64, const void* p, long long i) {
    return is64 ? (int)((const long long*)p)[i] : ((const int*)p)[i];
}
__device__ __forceinline__ v8s ld8(const __hip_bfloat16* p) { return *(const v8s*)p; }

// ---------- dtype probe (parallel): flags[0]=fp32 floats, flags[1]=int64 indices
__global__ void k_probe(const unsigned* __restrict__ xw, int nw_safe,
                        const unsigned* __restrict__ ew, int* __restrict__ flags) {
    __shared__ int cnt[2];
    int t = threadIdx.x;
    if (t < 2) cnt[t] = 0;
    __syncthreads();
    unsigned w = xw[(unsigned)(t * 9973) % (unsigned)nw_safe];
    unsigned lo = w & 0xffffu;
    unsigned exp = (lo >> 7) & 0xffu;
    if (lo != 0u && (exp < 90u || exp > 160u)) atomicAdd(&cnt[0], 1);
    if (ew[2 * t + 1] == 0u) atomicAdd(&cnt[1], 1);
    __syncthreads();
    if (t == 0) { flags[0] = (2 * cnt[0] > 256) ? 1 : 0; flags[1] = (cnt[1] >= 200) ? 1 : 0; }
}

// ---------- params: Pf fp32 vectors + transposed bf16 weights ----------
// Pf: as0@0[64] ad0@64[64] bias0@128[64] as1@192[32] ad1@224[32] bias1@256[32]
// Wg (bf16): Wt0@0 [64][128], sWt0@8192 [64][128], Wt1@16384 [32][64], sWt1@18432 [32][64]
__global__ void k_params(const int* __restrict__ flags,
                         const void* W0, const void* sW0, const void* as0, const void* ad0,
                         const void* b0, const void* sb0, const void* W1, const void* sW1,
                         const void* as1, const void* ad1, const void* b1, const void* sb1,
                         float* __restrict__ Pf, __hip_bfloat16* __restrict__ Wg) {
    int f = flags[0];
    int t = blockIdx.x * blockDim.x + threadIdx.x;
    int T = gridDim.x * blockDim.x;
    for (int i = t; i < 8192; i += T) {
        int n = i >> 7, k = i & 127;
        Wg[i]        = f2bf(ldany(f, W0,  k * 64 + n));
        Wg[8192 + i] = f2bf(ldany(f, sW0, k * 64 + n));
    }
    for (int i = t; i < 2048; i += T) {
        int n = i >> 6, k = i & 63;
        Wg[16384 + i] = f2bf(ldany(f, W1,  k * 32 + n));
        Wg[18432 + i] = f2bf(ldany(f, sW1, k * 32 + n));
    }
    if (t < 64) {
        Pf[t]       = ldany(f, as0, t);
        Pf[64 + t]  = ldany(f, ad0, t);
        Pf[128 + t] = ldany(f, b0, t) + ldany(f, sb0, t);
    }
    if (t < 32) {
        Pf[192 + t] = ldany(f, as1, t);
        Pf[224 + t] = ldany(f, ad1, t);
        Pf[256 + t] = ldany(f, b1, t) + ldany(f, sb1, t);
    }
}

__global__ void k_zero(int* __restrict__ p, int n) {
    int i = blockIdx.x * blockDim.x + threadIdx.x;
    if (i < n) p[i] = 0;
}

// ---------- CSR build ----------
__global__ void k_deg(const void* __restrict__ ei, const int* __restrict__ flags,
                      int E, int N, int* __restrict__ deg) {
    int i = blockIdx.x * blockDim.x + threadIdx.x;
    if (i < E) {
        unsigned d = (unsigned)ldidx(flags[1], ei, (long long)E + i);
        if (d < (unsigned)N) atomicAdd(&deg[d], 1);
    }
}

// multi-block scan, 3 phases
__global__ void k_scan1(const int* __restrict__ deg, int N,
                        int* __restrict__ rowptr, int* __restrict__ bsum) {
    __shared__ int sh[1024];
    int t = threadIdx.x;
    int idx = blockIdx.x * 1024 + t;
    int v = (idx < N) ? deg[idx] : 0;
    sh[t] = v;
    __syncthreads();
    for (int off = 1; off < 1024; off <<= 1) {
        int xv = (t >= off) ? sh[t - off] : 0;
        __syncthreads();
        sh[t] += xv;
        __syncthreads();
    }
    if (idx < N) rowptr[idx] = sh[t] - v;     // block-local exclusive
    if (t == 1023) bsum[blockIdx.x] = sh[1023];
}

__global__ void k_scan2(int* __restrict__ bsum, int B, int* __restrict__ rowptr, int N) {
    __shared__ int sh[1024];
    int t = threadIdx.x;
    int v = (t < B) ? bsum[t] : 0;
    sh[t] = v;
    __syncthreads();
    for (int off = 1; off < 1024; off <<= 1) {
        int xv = (t >= off) ? sh[t - off] : 0;
        __syncthreads();
        sh[t] += xv;
        __syncthreads();
    }
    if (t < B) bsum[t] = sh[t] - v;           // exclusive block offsets
    if (t == 1023) rowptr[N] = sh[1023];      // total
}

__global__ void k_scan3(int N, int* __restrict__ rowptr, const int* __restrict__ bsum,
                        int* __restrict__ cursor) {
    int idx = blockIdx.x * 1024 + threadIdx.x;
    if (idx < N) {
        int r = rowptr[idx] + bsum[blockIdx.x];
        rowptr[idx] = r;
        cursor[idx] = r;
    }
}

__global__ void k_fill(const void* __restrict__ ei, const int* __restrict__ flags,
                       int E, int N, int* __restrict__ cursor, int* __restrict__ csr_src) {
    int i = blockIdx.x * blockDim.x + threadIdx.x;
    if (i < E) {
        int f = flags[1];
        unsigned d = (unsigned)ldidx(f, ei, (long long)E + i);
        if (d < (unsigned)N) {
            int p = atomicAdd(&cursor[d], 1);
            if ((unsigned)p < (unsigned)E) csr_src[p] = ldidx(f, ei, i);
        }
    }
}

// ---------- layer 0 transform: MFMA 16x16x32 bf16, 64-node tile per block ----------
__global__ __launch_bounds__(256) void k_l0(
    const void* __restrict__ x, const int* __restrict__ flags,
    const float* __restrict__ Pf, const __hip_bfloat16* __restrict__ Wg, int N,
    __hip_bfloat16* __restrict__ h0, __hip_bfloat16* __restrict__ skip0,
    float* __restrict__ ssrc, float* __restrict__ sdst) {
    // stride 136 (=17*8) bf16: breaks stride-128 16-way LDS bank conflict
    __shared__ __hip_bfloat16 sm[26112];        // xs[64][136] | wt0[64][136] | wts[64][136]
    __hip_bfloat16* xs  = sm;
    __hip_bfloat16* wt0 = sm + 8704;
    __hip_bfloat16* wts = sm + 17408;
    int tid = threadIdx.x;
    int f = flags[0];
    int tile = blockIdx.x * 64;

    // stage weights (already transposed bf16 [64][128])
    for (int i = tid * 4; i < 8192; i += 1024) {
        int r = i >> 7, k = i & 127;
        __hip_bfloat16* d0 = &wt0[r * 136 + k];
        __hip_bfloat16* d1 = &wts[r * 136 + k];
#pragma unroll
        for (int u = 0; u < 4; u++) { d0[u] = Wg[i + u]; d1[u] = Wg[8192 + i + u]; }
    }
    // stage x tile -> bf16
    for (int i = tid * 4; i < 8192; i += 1024) {
        int r = i >> 7, k = i & 127;
        int g = tile + r; if (g >= N) g = N - 1;
        __hip_bfloat16* dx = &xs[r * 136 + k];
        if (f) {
            const float* xp = (const float*)x + (size_t)g * 128 + k;
#pragma unroll
            for (int u = 0; u < 4; u++) dx[u] = f2bf(xp[u]);
        } else {
            const __hip_bfloat16* xp = (const __hip_bfloat16*)x + (size_t)g * 128 + k;
#pragma unroll
            for (int u = 0; u < 4; u++) dx[u] = xp[u];
        }
    }
    __syncthreads();

    int lane = tid & 63, w = tid >> 6;
    int n16 = lane & 15, quad = lane >> 4;
    v4f zf = {0.f, 0.f, 0.f, 0.f};
    v4f acc_h[4], acc_s[4];
#pragma unroll
    for (int t = 0; t < 4; t++) { acc_h[t] = zf; acc_s[t] = zf; }

    int arow = (w << 4) + n16;
#pragma unroll
    for (int s = 0; s < 4; s++) {
        v8s a = ld8(&xs[arow * 136 + s * 32 + (quad << 3)]);
#pragma unroll
        for (int t = 0; t < 4; t++) {
            v8s bh = ld8(&wt0[(t * 16 + n16) * 136 + s * 32 + (quad << 3)]);
            acc_h[t] = __builtin_amdgcn_mfma_f32_16x16x32_bf16(a, bh, acc_h[t], 0, 0, 0);
            v8s bs = ld8(&wts[(t * 16 + n16) * 136 + s * 32 + (quad << 3)]);
            acc_s[t] = __builtin_amdgcn_mfma_f32_16x16x32_bf16(a, bs, acc_s[t], 0, 0, 0);
        }
    }

    // epilogue: C layout col=lane&15 (channel), row=(lane>>4)*4+reg (node)
    int mbase = tile + (w << 4) + (quad << 2);
    float ps[4] = {0, 0, 0, 0}, pd[4] = {0, 0, 0, 0};
#pragma unroll
    for (int t = 0; t < 4; t++) {
        int ch = t * 16 + n16;
        float av = Pf[ch];
        float dv = Pf[64 + ch];
        float bv = Pf[128 + ch];
#pragma unroll
        for (int r = 0; r < 4; r++) {
            float hv = sane(acc_h[t][r]);
            float sv = sane(acc_s[t][r] + bv);
            int node = mbase + r;
            if (node < N) {
                h0[(size_t)node * 64 + ch] = f2bf(hv);
                skip0[(size_t)node * 64 + ch] = f2bf(sv);
            }
            ps[r] += hv * av;
            pd[r] += hv * dv;
        }
    }
#pragma unroll
    for (int m = 1; m <= 8; m <<= 1) {
#pragma unroll
        for (int r = 0; r < 4; r++) {
            ps[r] += __shfl_xor(ps[r], m, 64);
            pd[r] += __shfl_xor(pd[r], m, 64);
        }
    }
    if (n16 == 0) {
#pragma unroll
        for (int r = 0; r < 4; r++) {
            int node = mbase + r;
            if (node < N) { ssrc[node] = sane(ps[r]); sdst[node] = sane(pd[r]); }
        }
    }
}

// ---------- layer 0 aggregation + skip + ELU; hact IN-PLACE over skip0 ----------
__global__ __launch_bounds__(256) void k_l0_agg(
    const int* __restrict__ rowptr, const int* __restrict__ csr_src,
    const float* __restrict__ ssrc, const float* __restrict__ sdst,
    const __hip_bfloat16* __restrict__ h0,
    int N, __hip_bfloat16* __restrict__ skip0_hact) {
    int wave = threadIdx.x >> 6, lane = threadIdx.x & 63;
    int n = blockIdx.x * 4 + wave;
    if (n >= N) return;
    float sd = sdst[n];
    float e = ssrc[n] + sd;
    e = eclampf(e > 0.f ? e : NEG_SLOPE * e);
    float w = __expf(e);
    float denom = w;
    float acc = w * sane(bf2f(h0[(size_t)n * 64 + lane]));
    int beg = rowptr[n], end = rowptr[n + 1];
    for (int j = beg; j < end; j++) {
        int s = csr_src[j];
        if ((unsigned)s >= (unsigned)N) continue;
        float ej = ssrc[s] + sd;
        ej = eclampf(ej > 0.f ? ej : NEG_SLOPE * ej);
        float wj = __expf(ej);
        denom += wj;
        acc += wj * sane(bf2f(h0[(size_t)s * 64 + lane]));
    }
    float v = sane(acc / denom + bf2f(skip0_hact[(size_t)n * 64 + lane]));
    v = v > 0.f ? v : (__expf(v) - 1.f);   // ELU
    skip0_hact[(size_t)n * 64 + lane] = f2bf(v);
}

// ---------- layer 1 transform: MFMA, Fin=64, C=32 ----------
__global__ __launch_bounds__(256) void k_l1(
    const __hip_bfloat16* __restrict__ hact,
    const float* __restrict__ Pf, const __hip_bfloat16* __restrict__ Wg, int N,
    __hip_bfloat16* __restrict__ h1, __hip_bfloat16* __restrict__ skip1,
    float* __restrict__ ssrc, float* __restrict__ sdst) {
    __shared__ __hip_bfloat16 sm[9216];         // xs[64][72] | wt1[32][72] | ws1[32][72]
    __hip_bfloat16* xs  = sm;
    __hip_bfloat16* wt1 = sm + 4608;
    __hip_bfloat16* ws1 = sm + 6912;
    int tid = threadIdx.x;
    int tile = blockIdx.x * 64;

    for (int i = tid * 4; i < 2048; i += 1024) {
        int r = i >> 6, k = i & 63;
        __hip_bfloat16* d0 = &wt1[r * 72 + k];
        __hip_bfloat16* d1 = &ws1[r * 72 + k];
#pragma unroll
        for (int u = 0; u < 4; u++) { d0[u] = Wg[16384 + i + u]; d1[u] = Wg[18432 + i + u]; }
    }
    for (int i = tid * 4; i < 4096; i += 1024) {
        int r = i >> 6, k = i & 63;
        int g = tile + r; if (g >= N) g = N - 1;
        __hip_bfloat16* dx = &xs[r * 72 + k];
        const __hip_bfloat16* xp = hact + (size_t)g * 64 + k;
#pragma unroll
        for (int u = 0; u < 4; u++) dx[u] = xp[u];
    }
    __syncthreads();

    int lane = tid & 63, w = tid >> 6;
    int n16 = lane & 15, quad = lane >> 4;
    v4f zf = {0.f, 0.f, 0.f, 0.f};
    v4f acc_h[2], acc_s[2];
#pragma unroll
    for (int t = 0; t < 2; t++) { acc_h[t] = zf; acc_s[t] = zf; }

    int arow = (w << 4) + n16;
#pragma unroll
    for (int s = 0; s < 2; s++) {
        v8s a = ld8(&xs[arow * 72 + s * 32 + (quad << 3)]);
#pragma unroll
        for (int t = 0; t < 2; t++) {
            v8s bh = ld8(&wt1[(t * 16 + n16) * 72 + s * 32 + (quad << 3)]);
            acc_h[t] = __builtin_amdgcn_mfma_f32_16x16x32_bf16(a, bh, acc_h[t], 0, 0, 0);
            v8s bs = ld8(&ws1[(t * 16 + n16) * 72 + s * 32 + (quad << 3)]);
            acc_s[t] = __builtin_amdgcn_mfma_f32_16x16x32_bf16(a, bs, acc_s[t], 0, 0, 0);
        }
    }

    int mbase = tile + (w << 4) + (quad << 2);
    float ps[4] = {0, 0, 0, 0}, pd[4] = {0, 0, 0, 0};
#pragma unroll
    for (int t = 0; t < 2; t++) {
        int ch = t * 16 + n16;
        float av = Pf[192 + ch];
        float dv = Pf[224 + ch];
        float bv = Pf[256 + ch];
#pragma unroll
        for (int r = 0; r < 4; r++) {
            float hv = sane(acc_h[t][r]);
            float sv = sane(acc_s[t][r] + bv);
            int node = mbase + r;
            if (node < N) {
                h1[(size_t)node * 32 + ch] = f2bf(hv);
                skip1[(size_t)node * 32 + ch] = f2bf(sv);
            }
            ps[r] += hv * av;
            pd[r] += hv * dv;
        }
    }
#pragma unroll
    for (int m = 1; m <= 8; m <<= 1) {
#pragma unroll
        for (int r = 0; r < 4; r++) {
            ps[r] += __shfl_xor(ps[r], m, 64);
            pd[r] += __shfl_xor(pd[r], m, 64);
        }
    }
    if (n16 == 0) {
#pragma unroll
        for (int r = 0; r < 4; r++) {
            int node = mbase + r;
            if (node < N) { ssrc[node] = sane(ps[r]); sdst[node] = sane(pd[r]); }
        }
    }
}

// ---------- layer 1 aggregation + skip + log_softmax + FP32 store ----------
__global__ __launch_bounds__(256) void k_l1_agg(
    const int* __restrict__ rowptr, const int* __restrict__ csr_src,
    const float* __restrict__ ssrc, const float* __restrict__ sdst,
    const __hip_bfloat16* __restrict__ h1, const __hip_bfloat16* __restrict__ skip1,
    int N, float* __restrict__ out) {
    int half = threadIdx.x >> 5, lane = threadIdx.x & 31;
    int n = blockIdx.x * 8 + half;
    if (n >= N) return;
    float sd = sdst[n];
    float e = ssrc[n] + sd;
    e = eclampf(e > 0.f ? e : NEG_SLOPE * e);
    float w = __expf(e);
    float denom = w;
    float acc = w * sane(bf2f(h1[(size_t)n * 32 + lane]));
    int beg = rowptr[n], end = rowptr[n + 1];
    for (int j = beg; j < end; j++) {
        int s = csr_src[j];
        if ((unsigned)s >= (unsigned)N) continue;
        float ej = ssrc[s] + sd;
        ej = eclampf(ej > 0.f ? ej : NEG_SLOPE * ej);
        float wj = __expf(ej);
        denom += wj;
        acc += wj * sane(bf2f(h1[(size_t)s * 32 + lane]));
    }
    float o = sane(acc / denom + bf2f(skip1[(size_t)n * 32 + lane]));
    float m = o;
#pragma unroll
    for (int k = 16; k >= 1; k >>= 1) m = fmaxf(m, __shfl_xor(m, k, 32));
    float ex = __expf(o - m);
    float ssum = ex;
#pragma unroll
    for (int k = 16; k >= 1; k >>= 1) ssum += __shfl_xor(ssum, k, 32);
    float res = o - m - __logf(ssum);
    if (!isfinite(res)) res = 0.f;
    out[(size_t)n * 32 + lane] = res;
}

__global__ void k_sentinel(float* __restrict__ out, int n, float val) {
    int i = blockIdx.x * blockDim.x + threadIdx.x;
    if (i < n) out[i] = val;
}

extern "C" void kernel_launch(void* const* d_in, const int* in_sizes, int n_in,
                              void* d_out, int out_size, void* d_ws, size_t ws_size,
                              hipStream_t stream) {
    const void* x  = d_in[0];
    const void* ei = d_in[1];
    float* out = (float*)d_out;

    int N = in_sizes[0] / 128;
    int E = in_sizes[1] / 2;

    char* ws = (char*)d_ws;
    size_t off = 0;
    auto alloc = [&](size_t bytes) -> char* {
        char* p = ws + off;
        off += (bytes + 255) & ~(size_t)255;
        return p;
    };
    int*   flags   = (int*)alloc(2 * 4);
    float* Pf      = (float*)alloc(288 * 4);
    __hip_bfloat16* Wg = (__hip_bfloat16*)alloc(20480 * 2);
    int*   rowptr  = (int*)alloc((size_t)(N + 1) * 4);
    int*   cursor  = (int*)alloc((size_t)N * 4);          // -> ssrc overlay after CSR
    float* sdst01  = (float*)alloc((size_t)N * 4);
    int*   bsum    = (int*)alloc(1024 * 4);
    int*   csr_src = (int*)alloc((size_t)E * 4);
    __hip_bfloat16* h0    = (__hip_bfloat16*)alloc((size_t)N * 64 * 2); // -> h1+skip1
    __hip_bfloat16* skip0 = (__hip_bfloat16*)alloc((size_t)N * 64 * 2); // -> hact in place
    size_t required = off;

    if (ws_size < required) {
        float mb = (float)(double)(ws_size >> 20);
        k_sentinel<<<(out_size + 255) / 256, 256, 0, stream>>>(out, out_size, mb);
        return;
    }

    float* ssrc01 = (float*)cursor;
    __hip_bfloat16* h1    = h0;
    __hip_bfloat16* skip1 = h0 + (size_t)N * 32;

    k_probe<<<1, 256, 0, stream>>>((const unsigned*)x, N * 64, (const unsigned*)ei, flags);
    k_params<<<40, 256, 0, stream>>>(flags, d_in[2], d_in[6], d_in[3], d_in[4],
                                     d_in[5], d_in[7], d_in[8], d_in[12],
                                     d_in[9], d_in[10], d_in[11], d_in[13], Pf, Wg);

    // CSR build (multi-block scan)
    int B = (N + 1023) / 1024;
    k_zero<<<(N + 255) / 256, 256, 0, stream>>>(cursor, N);
    k_deg<<<(E + 255) / 256, 256, 0, stream>>>(ei, flags, E, N, cursor);
    k_scan1<<<B, 1024, 0, stream>>>(cursor, N, rowptr, bsum);
    k_scan2<<<1, 1024, 0, stream>>>(bsum, B, rowptr, N);
    k_scan3<<<B, 1024, 0, stream>>>(N, rowptr, bsum, cursor);
    k_fill<<<(E + 255) / 256, 256, 0, stream>>>(ei, flags, E, N, cursor, csr_src);

    // layer 0
    k_l0<<<(N + 63) / 64, 256, 0, stream>>>(x, flags, Pf, Wg, N,
                                            h0, skip0, ssrc01, sdst01);
    k_l0_agg<<<(N + 3) / 4, 256, 0, stream>>>(rowptr, csr_src, ssrc01, sdst01,
                                              h0, N, skip0);
    // layer 1 (skip0 now holds hact)
    k_l1<<<(N + 63) / 64, 256, 0, stream>>>(skip0, Pf, Wg, N,
                                            h1, skip1, ssrc01, sdst01);
    k_l1_agg<<<(N + 7) / 8, 256, 0, stream>>>(rowptr, csr_src, ssrc01, sdst01,
                                              h1, skip1, N, out);
}

// Round 7
// 467.078 us; speedup vs baseline: 2.2848x; 1.3143x over previous
//
#include <hip/hip_runtime.h>
#include <hip/hip_bf16.h>
#include <math.h>

#define NEG_SLOPE 0.2f
#define ECLAMP 30.0f
#define HCLAMP 1.0e4f

typedef short v8s __attribute__((ext_vector_type(8)));
typedef float v4f __attribute__((ext_vector_type(4)));

__device__ __forceinline__ float bf2f(__hip_bfloat16 v) { return __bfloat162float(v); }
__device__ __forceinline__ __hip_bfloat16 f2bf(float v) { return __float2bfloat16(v); }
__device__ __forceinline__ float sane(float v)   { return fminf(fmaxf(v, -HCLAMP), HCLAMP); }
__device__ __forceinline__ float eclampf(float v){ return fminf(fmaxf(v, -ECLAMP), ECLAMP); }

__device__ __forceinline__ float ldany(int isf32, const void* p, int i) {
    return isf32 ? ((const float*)p)[i] : bf2f(((const __hip_bfloat16*)p)[i]);
}
__device__ __forceinline__ int ldidx(int is64, const void* p, long long i) {
    return is64 ? (int)((const long long*)p)[i] : ((const int*)p)[i];
}
__device__ __forceinline__ v8s ld8(const __hip_bfloat16* p) { return *(const v8s*)p; }

// leaky_relu + clamp + exp
__device__ __forceinline__ float ewgt(float e) {
    e = e > 0.f ? e : NEG_SLOPE * e;
    return __expf(eclampf(e));
}

// ---------- dtype probe ----------
__global__ void k_probe(const unsigned* __restrict__ xw, int nw_safe,
                        const unsigned* __restrict__ ew, int* __restrict__ flags) {
    __shared__ int cnt[2];
    int t = threadIdx.x;
    if (t < 2) cnt[t] = 0;
    __syncthreads();
    unsigned w = xw[(unsigned)(t * 9973) % (unsigned)nw_safe];
    unsigned lo = w & 0xffffu;
    unsigned exp = (lo >> 7) & 0xffu;
    if (lo != 0u && (exp < 90u || exp > 160u)) atomicAdd(&cnt[0], 1);
    if (ew[2 * t + 1] == 0u) atomicAdd(&cnt[1], 1);
    __syncthreads();
    if (t == 0) { flags[0] = (2 * cnt[0] > 256) ? 1 : 0; flags[1] = (cnt[1] >= 200) ? 1 : 0; }
}

// ---------- params: Pf fp32 vectors + transposed bf16 weights ----------
__global__ void k_params(const int* __restrict__ flags,
                         const void* W0, const void* sW0, const void* as0, const void* ad0,
                         const void* b0, const void* sb0, const void* W1, const void* sW1,
                         const void* as1, const void* ad1, const void* b1, const void* sb1,
                         float* __restrict__ Pf, __hip_bfloat16* __restrict__ Wg) {
    int f = flags[0];
    int t = blockIdx.x * blockDim.x + threadIdx.x;
    int T = gridDim.x * blockDim.x;
    for (int i = t; i < 8192; i += T) {
        int n = i >> 7, k = i & 127;
        Wg[i]        = f2bf(ldany(f, W0,  k * 64 + n));
        Wg[8192 + i] = f2bf(ldany(f, sW0, k * 64 + n));
    }
    for (int i = t; i < 2048; i += T) {
        int n = i >> 6, k = i & 63;
        Wg[16384 + i] = f2bf(ldany(f, W1,  k * 32 + n));
        Wg[18432 + i] = f2bf(ldany(f, sW1, k * 32 + n));
    }
    if (t < 64) {
        Pf[t]       = ldany(f, as0, t);
        Pf[64 + t]  = ldany(f, ad0, t);
        Pf[128 + t] = ldany(f, b0, t) + ldany(f, sb0, t);
    }
    if (t < 32) {
        Pf[192 + t] = ldany(f, as1, t);
        Pf[224 + t] = ldany(f, ad1, t);
        Pf[256 + t] = ldany(f, b1, t) + ldany(f, sb1, t);
    }
}

__global__ void k_zero(int* __restrict__ p, int n) {
    int i = blockIdx.x * blockDim.x + threadIdx.x;
    if (i < n) p[i] = 0;
}

// ---------- CSR build ----------
__global__ void k_deg(const void* __restrict__ ei, const int* __restrict__ flags,
                      int E, int N, int* __restrict__ deg) {
    int i = blockIdx.x * blockDim.x + threadIdx.x;
    if (i < E) {
        unsigned d = (unsigned)ldidx(flags[1], ei, (long long)E + i);
        if (d < (unsigned)N) atomicAdd(&deg[d], 1);
    }
}

__global__ void k_scan1(const int* __restrict__ deg, int N,
                        int* __restrict__ rowptr, int* __restrict__ bsum) {
    __shared__ int sh[1024];
    int t = threadIdx.x;
    int idx = blockIdx.x * 1024 + t;
    int v = (idx < N) ? deg[idx] : 0;
    sh[t] = v;
    __syncthreads();
    for (int off = 1; off < 1024; off <<= 1) {
        int xv = (t >= off) ? sh[t - off] : 0;
        __syncthreads();
        sh[t] += xv;
        __syncthreads();
    }
    if (idx < N) rowptr[idx] = sh[t] - v;
    if (t == 1023) bsum[blockIdx.x] = sh[1023];
}

__global__ void k_scan2(int* __restrict__ bsum, int B, int* __restrict__ rowptr, int N) {
    __shared__ int sh[1024];
    int t = threadIdx.x;
    int v = (t < B) ? bsum[t] : 0;
    sh[t] = v;
    __syncthreads();
    for (int off = 1; off < 1024; off <<= 1) {
        int xv = (t >= off) ? sh[t - off] : 0;
        __syncthreads();
        sh[t] += xv;
        __syncthreads();
    }
    if (t < B) bsum[t] = sh[t] - v;
    if (t == 1023) rowptr[N] = sh[1023];
}

__global__ void k_scan3(int N, int* __restrict__ rowptr, const int* __restrict__ bsum,
                        int* __restrict__ cursor) {
    int idx = blockIdx.x * 1024 + threadIdx.x;
    if (idx < N) {
        int r = rowptr[idx] + bsum[blockIdx.x];
        rowptr[idx] = r;
        cursor[idx] = r;
    }
}

__global__ void k_fill(const void* __restrict__ ei, const int* __restrict__ flags,
                       int E, int N, int* __restrict__ cursor, int* __restrict__ csr_src) {
    int i = blockIdx.x * blockDim.x + threadIdx.x;
    if (i < E) {
        int f = flags[1];
        unsigned d = (unsigned)ldidx(f, ei, (long long)E + i);
        if (d < (unsigned)N) {
            int p = atomicAdd(&cursor[d], 1);
            if ((unsigned)p < (unsigned)E) csr_src[p] = ldidx(f, ei, i);
        }
    }
}

// ---------- layer 0 transform: MFMA 16x16x32 bf16 ----------
__global__ __launch_bounds__(256) void k_l0(
    const void* __restrict__ x, const int* __restrict__ flags,
    const float* __restrict__ Pf, const __hip_bfloat16* __restrict__ Wg, int N,
    __hip_bfloat16* __restrict__ h0, __hip_bfloat16* __restrict__ skip0,
    float* __restrict__ ssrc, float* __restrict__ sdst) {
    __shared__ __hip_bfloat16 sm[26112];
    __hip_bfloat16* xs  = sm;
    __hip_bfloat16* wt0 = sm + 8704;
    __hip_bfloat16* wts = sm + 17408;
    int tid = threadIdx.x;
    int f = flags[0];
    int tile = blockIdx.x * 64;

    for (int i = tid * 4; i < 8192; i += 1024) {
        int r = i >> 7, k = i & 127;
        __hip_bfloat16* d0 = &wt0[r * 136 + k];
        __hip_bfloat16* d1 = &wts[r * 136 + k];
#pragma unroll
        for (int u = 0; u < 4; u++) { d0[u] = Wg[i + u]; d1[u] = Wg[8192 + i + u]; }
    }
    for (int i = tid * 4; i < 8192; i += 1024) {
        int r = i >> 7, k = i & 127;
        int g = tile + r; if (g >= N) g = N - 1;
        __hip_bfloat16* dx = &xs[r * 136 + k];
        if (f) {
            const float* xp = (const float*)x + (size_t)g * 128 + k;
#pragma unroll
            for (int u = 0; u < 4; u++) dx[u] = f2bf(xp[u]);
        } else {
            const __hip_bfloat16* xp = (const __hip_bfloat16*)x + (size_t)g * 128 + k;
#pragma unroll
            for (int u = 0; u < 4; u++) dx[u] = xp[u];
        }
    }
    __syncthreads();

    int lane = tid & 63, w = tid >> 6;
    int n16 = lane & 15, quad = lane >> 4;
    v4f zf = {0.f, 0.f, 0.f, 0.f};
    v4f acc_h[4], acc_s[4];
#pragma unroll
    for (int t = 0; t < 4; t++) { acc_h[t] = zf; acc_s[t] = zf; }

    int arow = (w << 4) + n16;
#pragma unroll
    for (int s = 0; s < 4; s++) {
        v8s a = ld8(&xs[arow * 136 + s * 32 + (quad << 3)]);
#pragma unroll
        for (int t = 0; t < 4; t++) {
            v8s bh = ld8(&wt0[(t * 16 + n16) * 136 + s * 32 + (quad << 3)]);
            acc_h[t] = __builtin_amdgcn_mfma_f32_16x16x32_bf16(a, bh, acc_h[t], 0, 0, 0);
            v8s bs = ld8(&wts[(t * 16 + n16) * 136 + s * 32 + (quad << 3)]);
            acc_s[t] = __builtin_amdgcn_mfma_f32_16x16x32_bf16(a, bs, acc_s[t], 0, 0, 0);
        }
    }

    int mbase = tile + (w << 4) + (quad << 2);
    float ps[4] = {0, 0, 0, 0}, pd[4] = {0, 0, 0, 0};
#pragma unroll
    for (int t = 0; t < 4; t++) {
        int ch = t * 16 + n16;
        float av = Pf[ch];
        float dv = Pf[64 + ch];
        float bv = Pf[128 + ch];
#pragma unroll
        for (int r = 0; r < 4; r++) {
            float hv = sane(acc_h[t][r]);
            float sv = sane(acc_s[t][r] + bv);
            int node = mbase + r;
            if (node < N) {
                h0[(size_t)node * 64 + ch] = f2bf(hv);
                skip0[(size_t)node * 64 + ch] = f2bf(sv);
            }
            ps[r] += hv * av;
            pd[r] += hv * dv;
        }
    }
#pragma unroll
    for (int m = 1; m <= 8; m <<= 1) {
#pragma unroll
        for (int r = 0; r < 4; r++) {
            ps[r] += __shfl_xor(ps[r], m, 64);
            pd[r] += __shfl_xor(pd[r], m, 64);
        }
    }
    if (n16 == 0) {
#pragma unroll
        for (int r = 0; r < 4; r++) {
            int node = mbase + r;
            if (node < N) { ssrc[node] = sane(ps[r]); sdst[node] = sane(pd[r]); }
        }
    }
}

// ---------- layer 0 aggregation (4x unrolled edge loop) + skip + ELU ----------
__global__ __launch_bounds__(256) void k_l0_agg(
    const int* __restrict__ rowptr, const int* __restrict__ csr_src,
    const float* __restrict__ ssrc, const float* __restrict__ sdst,
    const __hip_bfloat16* __restrict__ h0,
    int N, __hip_bfloat16* __restrict__ skip0_hact) {
    int wave = threadIdx.x >> 6, lane = threadIdx.x & 63;
    int n = blockIdx.x * 4 + wave;
    if (n >= N) return;
    float sd = sdst[n];
    float w = ewgt(ssrc[n] + sd);
    float den0 = w, den1 = 0.f, den2 = 0.f, den3 = 0.f;
    float acc0 = w * bf2f(h0[(size_t)n * 64 + lane]);
    float acc1 = 0.f, acc2 = 0.f, acc3 = 0.f;
    int beg = rowptr[n], end = rowptr[n + 1];
    int j = beg;
    for (; j + 4 <= end; j += 4) {
        int s0 = csr_src[j], s1 = csr_src[j + 1], s2 = csr_src[j + 2], s3 = csr_src[j + 3];
        bool v0 = (unsigned)s0 < (unsigned)N, v1 = (unsigned)s1 < (unsigned)N;
        bool v2 = (unsigned)s2 < (unsigned)N, v3 = (unsigned)s3 < (unsigned)N;
        s0 = v0 ? s0 : n; s1 = v1 ? s1 : n; s2 = v2 ? s2 : n; s3 = v3 ? s3 : n;
        float w0 = ewgt(ssrc[s0] + sd), w1 = ewgt(ssrc[s1] + sd);
        float w2 = ewgt(ssrc[s2] + sd), w3 = ewgt(ssrc[s3] + sd);
        w0 = v0 ? w0 : 0.f; w1 = v1 ? w1 : 0.f; w2 = v2 ? w2 : 0.f; w3 = v3 ? w3 : 0.f;
        float g0 = bf2f(h0[(size_t)s0 * 64 + lane]);
        float g1 = bf2f(h0[(size_t)s1 * 64 + lane]);
        float g2 = bf2f(h0[(size_t)s2 * 64 + lane]);
        float g3 = bf2f(h0[(size_t)s3 * 64 + lane]);
        den0 += w0; acc0 += w0 * g0;
        den1 += w1; acc1 += w1 * g1;
        den2 += w2; acc2 += w2 * g2;
        den3 += w3; acc3 += w3 * g3;
    }
    for (; j < end; j++) {
        int s = csr_src[j];
        if ((unsigned)s >= (unsigned)N) continue;
        float wj = ewgt(ssrc[s] + sd);
        den0 += wj;
        acc0 += wj * bf2f(h0[(size_t)s * 64 + lane]);
    }
    float denom = (den0 + den1) + (den2 + den3);
    float acc   = (acc0 + acc1) + (acc2 + acc3);
    float v = sane(acc / denom + bf2f(skip0_hact[(size_t)n * 64 + lane]));
    v = v > 0.f ? v : (__expf(v) - 1.f);   // ELU
    skip0_hact[(size_t)n * 64 + lane] = f2bf(v);
}

// ---------- layer 1 transform: MFMA, Fin=64, C=32 ----------
__global__ __launch_bounds__(256) void k_l1(
    const __hip_bfloat16* __restrict__ hact,
    const float* __restrict__ Pf, const __hip_bfloat16* __restrict__ Wg, int N,
    __hip_bfloat16* __restrict__ h1, __hip_bfloat16* __restrict__ skip1,
    float* __restrict__ ssrc, float* __restrict__ sdst) {
    __shared__ __hip_bfloat16 sm[9216];
    __hip_bfloat16* xs  = sm;
    __hip_bfloat16* wt1 = sm + 4608;
    __hip_bfloat16* ws1 = sm + 6912;
    int tid = threadIdx.x;
    int tile = blockIdx.x * 64;

    for (int i = tid * 4; i < 2048; i += 1024) {
        int r = i >> 6, k = i & 63;
        __hip_bfloat16* d0 = &wt1[r * 72 + k];
        __hip_bfloat16* d1 = &ws1[r * 72 + k];
#pragma unroll
        for (int u = 0; u < 4; u++) { d0[u] = Wg[16384 + i + u]; d1[u] = Wg[18432 + i + u]; }
    }
    for (int i = tid * 4; i < 4096; i += 1024) {
        int r = i >> 6, k = i & 63;
        int g = tile + r; if (g >= N) g = N - 1;
        __hip_bfloat16* dx = &xs[r * 72 + k];
        const __hip_bfloat16* xp = hact + (size_t)g * 64 + k;
#pragma unroll
        for (int u = 0; u < 4; u++) dx[u] = xp[u];
    }
    __syncthreads();

    int lane = tid & 63, w = tid >> 6;
    int n16 = lane & 15, quad = lane >> 4;
    v4f zf = {0.f, 0.f, 0.f, 0.f};
    v4f acc_h[2], acc_s[2];
#pragma unroll
    for (int t = 0; t < 2; t++) { acc_h[t] = zf; acc_s[t] = zf; }

    int arow = (w << 4) + n16;
#pragma unroll
    for (int s = 0; s < 2; s++) {
        v8s a = ld8(&xs[arow * 72 + s * 32 + (quad << 3)]);
#pragma unroll
        for (int t = 0; t < 2; t++) {
            v8s bh = ld8(&wt1[(t * 16 + n16) * 72 + s * 32 + (quad << 3)]);
            acc_h[t] = __builtin_amdgcn_mfma_f32_16x16x32_bf16(a, bh, acc_h[t], 0, 0, 0);
            v8s bs = ld8(&ws1[(t * 16 + n16) * 72 + s * 32 + (quad << 3)]);
            acc_s[t] = __builtin_amdgcn_mfma_f32_16x16x32_bf16(a, bs, acc_s[t], 0, 0, 0);
        }
    }

    int mbase = tile + (w << 4) + (quad << 2);
    float ps[4] = {0, 0, 0, 0}, pd[4] = {0, 0, 0, 0};
#pragma unroll
    for (int t = 0; t < 2; t++) {
        int ch = t * 16 + n16;
        float av = Pf[192 + ch];
        float dv = Pf[224 + ch];
        float bv = Pf[256 + ch];
#pragma unroll
        for (int r = 0; r < 4; r++) {
            float hv = sane(acc_h[t][r]);
            float sv = sane(acc_s[t][r] + bv);
            int node = mbase + r;
            if (node < N) {
                h1[(size_t)node * 32 + ch] = f2bf(hv);
                skip1[(size_t)node * 32 + ch] = f2bf(sv);
            }
            ps[r] += hv * av;
            pd[r] += hv * dv;
        }
    }
#pragma unroll
    for (int m = 1; m <= 8; m <<= 1) {
#pragma unroll
        for (int r = 0; r < 4; r++) {
            ps[r] += __shfl_xor(ps[r], m, 64);
            pd[r] += __shfl_xor(pd[r], m, 64);
        }
    }
    if (n16 == 0) {
#pragma unroll
        for (int r = 0; r < 4; r++) {
            int node = mbase + r;
            if (node < N) { ssrc[node] = sane(ps[r]); sdst[node] = sane(pd[r]); }
        }
    }
}

// ---------- layer 1 aggregation (4x unrolled) + skip + log_softmax ----------
__global__ __launch_bounds__(256) void k_l1_agg(
    const int* __restrict__ rowptr, const int* __restrict__ csr_src,
    const float* __restrict__ ssrc, const float* __restrict__ sdst,
    const __hip_bfloat16* __restrict__ h1, const __hip_bfloat16* __restrict__ skip1,
    int N, float* __restrict__ out) {
    int half = threadIdx.x >> 5, lane = threadIdx.x & 31;
    int n = blockIdx.x * 8 + half;
    if (n >= N) return;
    float sd = sdst[n];
    float w = ewgt(ssrc[n] + sd);
    float den0 = w, den1 = 0.f, den2 = 0.f, den3 = 0.f;
    float acc0 = w * bf2f(h1[(size_t)n * 32 + lane]);
    float acc1 = 0.f, acc2 = 0.f, acc3 = 0.f;
    int beg = rowptr[n], end = rowptr[n + 1];
    int j = beg;
    for (; j + 4 <= end; j += 4) {
        int s0 = csr_src[j], s1 = csr_src[j + 1], s2 = csr_src[j + 2], s3 = csr_src[j + 3];
        bool v0 = (unsigned)s0 < (unsigned)N, v1 = (unsigned)s1 < (unsigned)N;
        bool v2 = (unsigned)s2 < (unsigned)N, v3 = (unsigned)s3 < (unsigned)N;
        s0 = v0 ? s0 : n; s1 = v1 ? s1 : n; s2 = v2 ? s2 : n; s3 = v3 ? s3 : n;
        float w0 = ewgt(ssrc[s0] + sd), w1 = ewgt(ssrc[s1] + sd);
        float w2 = ewgt(ssrc[s2] + sd), w3 = ewgt(ssrc[s3] + sd);
        w0 = v0 ? w0 : 0.f; w1 = v1 ? w1 : 0.f; w2 = v2 ? w2 : 0.f; w3 = v3 ? w3 : 0.f;
        float g0 = bf2f(h1[(size_t)s0 * 32 + lane]);
        float g1 = bf2f(h1[(size_t)s1 * 32 + lane]);
        float g2 = bf2f(h1[(size_t)s2 * 32 + lane]);
        float g3 = bf2f(h1[(size_t)s3 * 32 + lane]);
        den0 += w0; acc0 += w0 * g0;
        den1 += w1; acc1 += w1 * g1;
        den2 += w2; acc2 += w2 * g2;
        den3 += w3; acc3 += w3 * g3;
    }
    for (; j < end; j++) {
        int s = csr_src[j];
        if ((unsigned)s >= (unsigned)N) continue;
        float wj = ewgt(ssrc[s] + sd);
        den0 += wj;
        acc0 += wj * bf2f(h1[(size_t)s * 32 + lane]);
    }
    float denom = (den0 + den1) + (den2 + den3);
    float acc   = (acc0 + acc1) + (acc2 + acc3);
    float o = sane(acc / denom + bf2f(skip1[(size_t)n * 32 + lane]));
    float m = o;
#pragma unroll
    for (int k = 16; k >= 1; k >>= 1) m = fmaxf(m, __shfl_xor(m, k, 32));
    float ex = __expf(o - m);
    float ssum = ex;
#pragma unroll
    for (int k = 16; k >= 1; k >>= 1) ssum += __shfl_xor(ssum, k, 32);
    float res = o - m - __logf(ssum);
    if (!isfinite(res)) res = 0.f;
    out[(size_t)n * 32 + lane] = res;
}

__global__ void k_sentinel(float* __restrict__ out, int n, float val) {
    int i = blockIdx.x * blockDim.x + threadIdx.x;
    if (i < n) out[i] = val;
}

extern "C" void kernel_launch(void* const* d_in, const int* in_sizes, int n_in,
                              void* d_out, int out_size, void* d_ws, size_t ws_size,
                              hipStream_t stream) {
    const void* x  = d_in[0];
    const void* ei = d_in[1];
    float* out = (float*)d_out;

    int N = in_sizes[0] / 128;
    int E = in_sizes[1] / 2;

    char* ws = (char*)d_ws;
    size_t off = 0;
    auto alloc = [&](size_t bytes) -> char* {
        char* p = ws + off;
        off += (bytes + 255) & ~(size_t)255;
        return p;
    };
    int*   flags   = (int*)alloc(2 * 4);
    float* Pf      = (float*)alloc(288 * 4);
    __hip_bfloat16* Wg = (__hip_bfloat16*)alloc(20480 * 2);
    int*   rowptr  = (int*)alloc((size_t)(N + 1) * 4);
    int*   cursor  = (int*)alloc((size_t)N * 4);          // -> ssrc overlay after CSR
    float* sdst01  = (float*)alloc((size_t)N * 4);
    int*   bsum    = (int*)alloc(1024 * 4);
    int*   csr_src = (int*)alloc((size_t)E * 4);
    __hip_bfloat16* h0    = (__hip_bfloat16*)alloc((size_t)N * 64 * 2); // -> h1+skip1
    __hip_bfloat16* skip0 = (__hip_bfloat16*)alloc((size_t)N * 64 * 2); // -> hact in place
    size_t required = off;

    if (ws_size < required) {
        float mb = (float)(double)(ws_size >> 20);
        k_sentinel<<<(out_size + 255) / 256, 256, 0, stream>>>(out, out_size, mb);
        return;
    }

    float* ssrc01 = (float*)cursor;
    __hip_bfloat16* h1    = h0;
    __hip_bfloat16* skip1 = h0 + (size_t)N * 32;

    k_probe<<<1, 256, 0, stream>>>((const unsigned*)x, N * 64, (const unsigned*)ei, flags);
    k_params<<<40, 256, 0, stream>>>(flags, d_in[2], d_in[6], d_in[3], d_in[4],
                                     d_in[5], d_in[7], d_in[8], d_in[12],
                                     d_in[9], d_in[10], d_in[11], d_in[13], Pf, Wg);

    int B = (N + 1023) / 1024;
    k_zero<<<(N + 255) / 256, 256, 0, stream>>>(cursor, N);
    k_deg<<<(E + 255) / 256, 256, 0, stream>>>(ei, flags, E, N, cursor);
    k_scan1<<<B, 1024, 0, stream>>>(cursor, N, rowptr, bsum);
    k_scan2<<<1, 1024, 0, stream>>>(bsum, B, rowptr, N);
    k_scan3<<<B, 1024, 0, stream>>>(N, rowptr, bsum, cursor);
    k_fill<<<(E + 255) / 256, 256, 0, stream>>>(ei, flags, E, N, cursor, csr_src);

    k_l0<<<(N + 63) / 64, 256, 0, stream>>>(x, flags, Pf, Wg, N,
                                            h0, skip0, ssrc01, sdst01);
    k_l0_agg<<<(N + 3) / 4, 256, 0, stream>>>(rowptr, csr_src, ssrc01, sdst01,
                                              h0, N, skip0);
    k_l1<<<(N + 63) / 64, 256, 0, stream>>>(skip0, Pf, Wg, N,
                                            h1, skip1, ssrc01, sdst01);
    k_l1_agg<<<(N + 7) / 8, 256, 0, stream>>>(rowptr, csr_src, ssrc01, sdst01,
                                              h1, skip1, N, out);
}